// Round 5
// baseline (370.439 us; speedup 1.0000x reference)
//
#include <hip/hip_runtime.h>
#include <hip/hip_bf16.h>
#include <cstdint>
#include <cstddef>

#define D_MODEL 1024
#define SEQ     2048
#define BATCH   4
#define NHEAD   16
#define HD      64
#define MROWS   (BATCH * SEQ)   // 8192

typedef __attribute__((ext_vector_type(8))) short  short8;    // 8 bf16 (4 VGPRs)
typedef __attribute__((ext_vector_type(4))) float  floatx4;   // MFMA acc
typedef __attribute__((ext_vector_type(4))) unsigned short ushort4v; // 8B pack
typedef unsigned short u16;

__device__ __forceinline__ u16 f2bf(float x) {
    __hip_bfloat16 h = __float2bfloat16(x);
    return *(u16*)&h;
}

// async global->LDS, 16B per lane. LDS dest = wave-uniform base + lane*16.
__device__ __forceinline__ void async_copy16(const u16* g, u16* l) {
    __builtin_amdgcn_global_load_lds(
        (const __attribute__((address_space(1))) void*)g,
        (__attribute__((address_space(3))) void*)l, 16, 0, 0);
}

// ---------------------------------------------------------------------------
// fp32 -> bf16 converts: 4 weight tensors (1M elems) + 3 activation tensors
// (8.39M elems). 8 elems/thread, grid.y selects tensor, early-exit past n.
// ---------------------------------------------------------------------------
__device__ __forceinline__ void cvt8(const float* s, u16* d, size_t i) {
    const float4 a = *(const float4*)(s + i);
    const float4 b = *(const float4*)(s + i + 4);
    short8 o;
    o[0] = (short)f2bf(a.x); o[1] = (short)f2bf(a.y);
    o[2] = (short)f2bf(a.z); o[3] = (short)f2bf(a.w);
    o[4] = (short)f2bf(b.x); o[5] = (short)f2bf(b.y);
    o[6] = (short)f2bf(b.z); o[7] = (short)f2bf(b.w);
    *(short8*)(d + i) = o;
}

__global__ __launch_bounds__(256) void cvt7(
    const float* __restrict__ s0, const float* __restrict__ s1,
    const float* __restrict__ s2, const float* __restrict__ s3,
    const float* __restrict__ s4, const float* __restrict__ s5,
    const float* __restrict__ s6,
    u16* __restrict__ d0, u16* __restrict__ d1,
    u16* __restrict__ d2, u16* __restrict__ d3,
    u16* __restrict__ d4, u16* __restrict__ d5,
    u16* __restrict__ d6)
{
    const int y = blockIdx.y;
    const float* s;
    u16* d;
    size_t n;
    switch (y) {
        case 0: s = s0; d = d0; n = (size_t)D_MODEL * D_MODEL; break;
        case 1: s = s1; d = d1; n = (size_t)D_MODEL * D_MODEL; break;
        case 2: s = s2; d = d2; n = (size_t)D_MODEL * D_MODEL; break;
        case 3: s = s3; d = d3; n = (size_t)D_MODEL * D_MODEL; break;
        case 4: s = s4; d = d4; n = (size_t)MROWS * D_MODEL;   break;
        case 5: s = s5; d = d5; n = (size_t)MROWS * D_MODEL;   break;
        default: s = s6; d = d6; n = (size_t)MROWS * D_MODEL;  break;
    }
    const size_t i = ((size_t)blockIdx.x * 256 + threadIdx.x) * 8;
    if (i < n) cvt8(s, d, i);
}

// ---------------------------------------------------------------------------
// Fused QKV GEMM, pure bf16 (A pre-converted by cvt7). m97 structure:
// async global_load_lds staging for BOTH A and W. grid.z selects tensor.
// z=0,1 (Q,K): out bf16 [B,H,S,Hd] via LDS re-layout -> coalesced 16B
// stores (was 64 scalar u16 stores/thread). XOR row-swizzle on Ct: without
// it the column-strided read (256B row stride) is a 32-way bank conflict.
// z=2 (V): out bf16 [B,H,Hd,S] via LDS transpose (unchanged, proven).
// 128x128 tile, BK=64, 256 thr = 4 waves, 4x4 MFMA/wave.
// ---------------------------------------------------------------------------
__global__ __launch_bounds__(256) void gemm_qkv(
    const u16* __restrict__ Aq, const u16* __restrict__ Ak,
    const u16* __restrict__ Av,
    const u16* __restrict__ Wqp, const u16* __restrict__ Wkp,
    const u16* __restrict__ Wvp,
    const float* __restrict__ bqp, const float* __restrict__ bkp,
    const float* __restrict__ bvp,
    u16* __restrict__ oq, u16* __restrict__ ok, u16* __restrict__ ov)
{
    constexpr int K = D_MODEL;
    __shared__ __align__(16) u16 smem[16384];          // 32 KB
    u16 (*As)[64] = (u16(*)[64])smem;                  // [128][64]
    u16 (*Ws)[64] = (u16(*)[64])(smem + 8192);         // [128][64]

    const int z = blockIdx.z;
    const u16*   A    = z == 0 ? Aq  : (z == 1 ? Ak  : Av);
    const u16*   W    = z == 0 ? Wqp : (z == 1 ? Wkp : Wvp);
    const float* bias = z == 0 ? bqp : (z == 1 ? bkp : bvp);
    u16*         out  = z == 0 ? oq  : (z == 1 ? ok  : ov);

    const int bm = blockIdx.x * 128;
    const int bn = blockIdx.y * 128;
    const int t  = threadIdx.x;
    const int w  = t >> 6;
    const int l  = t & 63;
    const int li = l & 15;
    const int quad = l >> 4;
    const int wm = (w & 1) * 64;
    const int wn = (w >> 1) * 64;
    const int lrow = l >> 3;
    const int lcol = (l & 7) * 8;

    const u16* Ag = A + (size_t)bm * K;
    const u16* Wg = W + (size_t)bn * K;

    floatx4 acc[4][4];
    #pragma unroll
    for (int mi = 0; mi < 4; mi++)
        #pragma unroll
        for (int ni = 0; ni < 4; ni++) acc[mi][ni] = (floatx4){0.f,0.f,0.f,0.f};

    for (int kt = 0; kt < K; kt += 64) {
        __syncthreads();
        #pragma unroll
        for (int j = 0; j < 4; j++) {
            const int r = w * 32 + j * 8;
            async_copy16(Ag + (size_t)(r + lrow) * K + kt + lcol, &As[r][0]);
            async_copy16(Wg + (size_t)(r + lrow) * K + kt + lcol, &Ws[r][0]);
        }
        __syncthreads();

        #pragma unroll
        for (int ks = 0; ks < 2; ks++) {
            short8 af[4], bf[4];
            #pragma unroll
            for (int i = 0; i < 4; i++) {
                af[i] = *(const short8*)&As[wm + i * 16 + li][ks * 32 + quad * 8];
                bf[i] = *(const short8*)&Ws[wn + i * 16 + li][ks * 32 + quad * 8];
            }
            #pragma unroll
            for (int mi = 0; mi < 4; mi++)
                #pragma unroll
                for (int ni = 0; ni < 4; ni++)
                    acc[mi][ni] = __builtin_amdgcn_mfma_f32_16x16x32_bf16(
                        af[mi], bf[ni], acc[mi][ni], 0, 0, 0);
        }
    }

    if (z < 2) {   // [B,H,S,Hd] via LDS re-layout -> 8x short8 stores/thread
        u16 (*Ct)[128] = (u16(*)[128])smem;   // 32 KB, aliases As/Ws
        __syncthreads();
        #pragma unroll
        for (int mi = 0; mi < 4; mi++)
            #pragma unroll
            for (int ni = 0; ni < 4; ni++) {
                const int cl = wn + ni * 16 + li;
                const float bz = bias[bn + cl];
                #pragma unroll
                for (int reg = 0; reg < 4; reg++) {
                    const int rl = wm + mi * 16 + quad * 4 + reg;
                    // XOR-swizzle cols (16B granule) by row: bits 3-5 of cl
                    Ct[rl][cl ^ ((rl & 7) << 3)] = f2bf(acc[mi][ni][reg] + bz);
                }
            }
        __syncthreads();
        const int rl  = t & 127;          // tile row (s offset)
        const int hh  = t >> 7;           // head half within tile cols
        const int b   = bm >> 11;
        const int s   = (bm & (SEQ - 1)) + rl;
        const int h   = (bn >> 6) + hh;
        const int rsw = rl & 7;
        u16* dst = out + (((size_t)(b * NHEAD + h) * SEQ) + s) * HD;
        #pragma unroll
        for (int i = 0; i < 8; i++) {
            // physical granule (i^rsw) within half hh holds logical granule i
            *(short8*)(dst + i * 8) =
                *(const short8*)&Ct[rl][hh * 64 + ((i ^ rsw) * 8)];
        }
    } else {       // V: transpose tile in LDS, store [B,H,Hd,S]
        u16 (*Ct)[128] = (u16(*)[128])smem;
        __syncthreads();
        #pragma unroll
        for (int mi = 0; mi < 4; mi++)
            #pragma unroll
            for (int ni = 0; ni < 4; ni++) {
                const int cl = wn + ni * 16 + li;
                const float bz = bias[bn + cl];
                #pragma unroll
                for (int reg = 0; reg < 4; reg++) {
                    const int rl = wm + mi * 16 + quad * 4 + reg;
                    Ct[cl][rl] = f2bf(acc[mi][ni][reg] + bz);
                }
            }
        __syncthreads();
        const int cl   = t >> 1;
        const int half = t & 1;
        const int cg = bn + cl;
        const int h  = cg >> 6;
        const int hd = cg & 63;
        const int b  = bm >> 11;
        const int s0 = (bm & (SEQ - 1)) + half * 64;
        u16* dst = out + (((size_t)(b * NHEAD + h) * HD) + hd) * SEQ + s0;
        const short8* sp = (const short8*)&Ct[cl][half * 64];
        #pragma unroll
        for (int i = 0; i < 8; i++) ((short8*)dst)[i] = sp[i];
    }
}

// ---------------------------------------------------------------------------
// Output projection: out = H @ Wo^T + bo, fp32 out. H bf16, Wo bf16.
// m97 structure (async global_load_lds staging), unchanged.
// ---------------------------------------------------------------------------
__global__ __launch_bounds__(256) void gemm_out(
    const u16* __restrict__ A,
    const u16* __restrict__ W,
    const float* __restrict__ bias,
    float* __restrict__ out)
{
    constexpr int K = D_MODEL;
    __shared__ __align__(16) u16 smem[16384];
    u16 (*As)[64] = (u16(*)[64])smem;
    u16 (*Ws)[64] = (u16(*)[64])(smem + 8192);

    const int bm = blockIdx.x * 128;
    const int bn = blockIdx.y * 128;
    const int t  = threadIdx.x;
    const int w  = t >> 6;
    const int l  = t & 63;
    const int li = l & 15;
    const int quad = l >> 4;
    const int wm = (w & 1) * 64;
    const int wn = (w >> 1) * 64;
    const int lrow = l >> 3;
    const int lcol = (l & 7) * 8;

    const u16* Ag = A + (size_t)bm * K;
    const u16* Wg = W + (size_t)bn * K;

    floatx4 acc[4][4];
    #pragma unroll
    for (int mi = 0; mi < 4; mi++)
        #pragma unroll
        for (int ni = 0; ni < 4; ni++) acc[mi][ni] = (floatx4){0.f,0.f,0.f,0.f};

    for (int kt = 0; kt < K; kt += 64) {
        __syncthreads();
        #pragma unroll
        for (int j = 0; j < 4; j++) {
            const int r = w * 32 + j * 8;
            async_copy16(Ag + (size_t)(r + lrow) * K + kt + lcol, &As[r][0]);
            async_copy16(Wg + (size_t)(r + lrow) * K + kt + lcol, &Ws[r][0]);
        }
        __syncthreads();

        #pragma unroll
        for (int ks = 0; ks < 2; ks++) {
            short8 af[4], bf[4];
            #pragma unroll
            for (int i = 0; i < 4; i++) {
                af[i] = *(const short8*)&As[wm + i * 16 + li][ks * 32 + quad * 8];
                bf[i] = *(const short8*)&Ws[wn + i * 16 + li][ks * 32 + quad * 8];
            }
            #pragma unroll
            for (int mi = 0; mi < 4; mi++)
                #pragma unroll
                for (int ni = 0; ni < 4; ni++)
                    acc[mi][ni] = __builtin_amdgcn_mfma_f32_16x16x32_bf16(
                        af[mi], bf[ni], acc[mi][ni], 0, 0, 0);
        }
    }

    #pragma unroll
    for (int mi = 0; mi < 4; mi++)
        #pragma unroll
        for (int ni = 0; ni < 4; ni++) {
            const int c = bn + wn + ni * 16 + li;
            const float bz = bias[c];
            #pragma unroll
            for (int reg = 0; reg < 4; reg++) {
                const int r = bm + wm + mi * 16 + quad * 4 + reg;
                out[(size_t)r * D_MODEL + c] = acc[mi][ni][reg] + bz;
            }
        }
}

// ---------------------------------------------------------------------------
// Flash attention v6 (RESTORED from R3 — best measured: 97.1 µs).
//   R4's key-half-split Ps regressed (bank conflicts 6.3M->14.7M, occupancy
//   flat): reverted. v6 = register diet (per-kb fused softmax, sacc live =
//   8 regs) + __launch_bounds__(256,4) + 2-barrier single-buffer schedule:
//     β1: Ks(t)+mc(t) ready -> stage V(t); QK^T+softmax over the drain.
//     β2: V(t) drained    -> stage K(t+1)+mc(t+1); PV over the drain.
// S^T = K Q^T; p = exp2(s*CSCALE + mc); packed b64 P writes; XOR-swizzled
// K/V LDS. LDS = 8 + 8 + 18 + 0.25 KB = ~35KB.
// ---------------------------------------------------------------------------
#define LOG2E   1.44269504088896340736f
#define CSCALE  (0.125f * LOG2E)        // 1/sqrt(64) * log2(e)

__global__ __launch_bounds__(256, 4) void attn_mfma(
    const u16* __restrict__ Q,
    const u16* __restrict__ K,
    const u16* __restrict__ Vt,
    const int* __restrict__ mask,
    u16* __restrict__ H)
{
    __shared__ __align__(16) u16 Ks[64 * 64];     // 8 KB  [key][hd], swizzled
    __shared__ __align__(16) u16 Vs[64 * 64];     // 8 KB  [hd][key], swizzled
    __shared__ __align__(16) u16 Ps[4][32][72];   // 18 KB per-wave P [qrow][key]
    __shared__ __align__(16) float mc[64];        // 256 B mask bias

    const int bh  = blockIdx.y;
    const int b   = bh >> 4;
    const int h   = bh & 15;
    const int q0  = blockIdx.x * 128;
    const int t   = threadIdx.x;
    const int w   = t >> 6;
    const int l   = t & 63;
    const int li  = l & 15;
    const int quad  = l >> 4;
    const int lrow8 = l >> 3;
    const int gch   = (l & 7) ^ lrow8;   // XOR-swizzled global chunk
    const int swz   = li & 7;            // frag-read swizzle term

    short8 qf[2][2];
    #pragma unroll
    for (int qb = 0; qb < 2; qb++) {
        const u16* Qrow = Q + ((size_t)bh * SEQ + q0 + w * 32 + qb * 16 + li) * HD;
        qf[qb][0] = *(const short8*)(Qrow + quad * 8);
        qf[qb][1] = *(const short8*)(Qrow + 32 + quad * 8);
    }

    const u16* Kbh = K  + (size_t)bh * SEQ * HD;
    const u16* Vbh = Vt + (size_t)bh * HD * SEQ;
    const int* mg  = mask + (size_t)b * SEQ;

    floatx4 oacc[4][2];
    #pragma unroll
    for (int hm = 0; hm < 4; hm++)
        #pragma unroll
        for (int qb = 0; qb < 2; qb++) oacc[hm][qb] = (floatx4){0.f,0.f,0.f,0.f};
    float rs[2] = {0.f, 0.f};

    // prologue: stage K(0) + mc(0); drained by the first loop-top barrier
    #pragma unroll
    for (int j = 0; j < 2; j++) {
        const int rb = w * 16 + j * 8;
        async_copy16(Kbh + (size_t)(rb + lrow8) * HD + gch * 8, &Ks[rb * 64]);
    }
    if (t < 64) mc[t] = (mg[t] != 0) ? -16.0f : -1.0e9f;

    for (int kt = 0; kt < SEQ; kt += 64) {
        __syncthreads();   // β1: Ks(t)+mc(t) published; Vs free (PV(t-1) done)

        // stage V(t): drains at β2, overlapping QK^T + softmax
        #pragma unroll
        for (int j = 0; j < 2; j++) {
            const int rb = w * 16 + j * 8;
            async_copy16(Vbh + (size_t)(rb + lrow8) * SEQ + kt + gch * 8,
                         &Vs[rb * 64]);
        }

        // ---- S^T = K Q^T, softmax fused per kb (sacc live = 8 regs) -----
        #pragma unroll
        for (int kb = 0; kb < 4; kb++) {
            floatx4 s0 = (floatx4){0.f,0.f,0.f,0.f};
            floatx4 s1 = (floatx4){0.f,0.f,0.f,0.f};
            #pragma unroll
            for (int ks = 0; ks < 2; ks++) {
                const short8 kf = *(const short8*)
                    &Ks[(kb * 16 + li) * 64 + ((ks * 4 + quad) ^ swz) * 8];
                __builtin_amdgcn_s_setprio(1);
                s0 = __builtin_amdgcn_mfma_f32_16x16x32_bf16(kf, qf[0][ks], s0, 0, 0, 0);
                s1 = __builtin_amdgcn_mfma_f32_16x16x32_bf16(kf, qf[1][ks], s1, 0, 0, 0);
                __builtin_amdgcn_s_setprio(0);
            }
            const float4 m4 = *(const float4*)&mc[kb * 16 + quad * 4];
            {
                const float p0 = __builtin_amdgcn_exp2f(fmaf(s0[0], CSCALE, m4.x));
                const float p1 = __builtin_amdgcn_exp2f(fmaf(s0[1], CSCALE, m4.y));
                const float p2 = __builtin_amdgcn_exp2f(fmaf(s0[2], CSCALE, m4.z));
                const float p3 = __builtin_amdgcn_exp2f(fmaf(s0[3], CSCALE, m4.w));
                rs[0] += (p0 + p1) + (p2 + p3);
                ushort4v pk;
                pk[0] = f2bf(p0); pk[1] = f2bf(p1);
                pk[2] = f2bf(p2); pk[3] = f2bf(p3);
                *(ushort4v*)&Ps[w][li][kb * 16 + quad * 4] = pk;
            }
            {
                const float p0 = __builtin_amdgcn_exp2f(fmaf(s1[0], CSCALE, m4.x));
                const float p1 = __builtin_amdgcn_exp2f(fmaf(s1[1], CSCALE, m4.y));
                const float p2 = __builtin_amdgcn_exp2f(fmaf(s1[2], CSCALE, m4.z));
                const float p3 = __builtin_amdgcn_exp2f(fmaf(s1[3], CSCALE, m4.w));
                rs[1] += (p0 + p1) + (p2 + p3);
                ushort4v pk;
                pk[0] = f2bf(p0); pk[1] = f2bf(p1);
                pk[2] = f2bf(p2); pk[3] = f2bf(p3);
                *(ushort4v*)&Ps[w][16 + li][kb * 16 + quad * 4] = pk;
            }
        }

        __syncthreads();   // β2: V(t) drained; all waves done with Ks(t)/mc(t)

        if (kt + 64 < SEQ) {
            // stage K(t+1) + mc(t+1): drains at β1(t+1), overlapping PV
            #pragma unroll
            for (int j = 0; j < 2; j++) {
                const int rb = w * 16 + j * 8;
                async_copy16(Kbh + (size_t)(kt + 64 + rb + lrow8) * HD + gch * 8,
                             &Ks[rb * 64]);
            }
            if (t < 64) mc[t] = (mg[kt + 64 + t] != 0) ? -16.0f : -1.0e9f;
        }

        // ---- O^T += V^T P^T ---------------------------------------------
        #pragma unroll
        for (int ks = 0; ks < 2; ks++) {
            short8 pf[2];
            #pragma unroll
            for (int qb = 0; qb < 2; qb++)
                pf[qb] = *(const short8*)&Ps[w][qb * 16 + li][ks * 32 + quad * 8];
            __builtin_amdgcn_s_setprio(1);
            #pragma unroll
            for (int hm = 0; hm < 4; hm++) {
                const short8 vf = *(const short8*)&Vs[(hm * 16 + li) * 64 + ((ks * 4 + quad) ^ swz) * 8];
                #pragma unroll
                for (int qb = 0; qb < 2; qb++)
                    oacc[hm][qb] = __builtin_amdgcn_mfma_f32_16x16x32_bf16(
                        vf, pf[qb], oacc[hm][qb], 0, 0, 0);
            }
            __builtin_amdgcn_s_setprio(0);
        }
    }

    float linv[2];
    #pragma unroll
    for (int qb = 0; qb < 2; qb++) {
        float v = rs[qb];
        v += __shfl_xor(v, 16, 64);
        v += __shfl_xor(v, 32, 64);
        linv[qb] = 1.0f / v;
    }
    #pragma unroll
    for (int qb = 0; qb < 2; qb++) {
        const size_t row = (size_t)b * SEQ + q0 + w * 32 + qb * 16 + li;
        #pragma unroll
        for (int hm = 0; hm < 4; hm++) {
            ushort4v o;
            #pragma unroll
            for (int reg = 0; reg < 4; reg++)
                o[reg] = f2bf(oacc[hm][qb][reg] * linv[qb]);
            *(ushort4v*)&H[row * D_MODEL + h * 64 + hm * 16 + quad * 4] = o;
        }
    }
}

// ---------------------------------------------------------------------------
extern "C" void kernel_launch(void* const* d_in, const int* in_sizes, int n_in,
                              void* d_out, int out_size, void* d_ws, size_t ws_size,
                              hipStream_t stream)
{
    const float* query = (const float*)d_in[0];
    const float* key_  = (const float*)d_in[1];
    const float* value = (const float*)d_in[2];
    const int*   mask  = (const int*)  d_in[3];
    const float* Wq = (const float*)d_in[4];
    const float* bq = (const float*)d_in[5];
    const float* Wk = (const float*)d_in[6];
    const float* bk = (const float*)d_in[7];
    const float* Wv = (const float*)d_in[8];
    const float* bv = (const float*)d_in[9];
    const float* Wo = (const float*)d_in[10];
    const float* bo = (const float*)d_in[11];
    float* out = (float*)d_out;

    const size_t per = (size_t)BATCH * NHEAD * SEQ * HD;   // 8,388,608 elems
    const size_t wsz = (size_t)D_MODEL * D_MODEL;          // 1,048,576 elems
    u16* Qb  = (u16*)d_ws;          // projected Q [B,H,S,Hd]        16 MB
    u16* Kb  = Qb  + per;           // projected K [B,H,S,Hd]        16 MB
    u16* Vtb = Kb  + per;           // projected V^T [B,H,Hd,S]      16 MB
    u16* Wqb = Vtb + per;           // bf16 weights                   2 MB x4
    u16* Wkb = Wqb + wsz;
    u16* Wvb = Wkb + wsz;
    u16* Wob = Wvb + wsz;
    u16* Aqb = Wob + wsz;           // bf16 activations              16 MB x3
    u16* Akb = Aqb + per;
    u16* Avb = Akb + per;
    u16* Hb  = Aqb;                 // attention out: ALIASES Aqb (dead after
                                    // gemm_qkv).  Total ~104 MB.

    // 7-tensor fp32->bf16 convert: weights (y=0..3) + activations (y=4..6)
    cvt7<<<dim3((per / 8 + 255) / 256, 7), 256, 0, stream>>>(
        Wq, Wk, Wv, Wo, query, key_, value,
        Wqb, Wkb, Wvb, Wob, Aqb, Akb, Avb);

    gemm_qkv<<<dim3(MROWS / 128, D_MODEL / 128, 3), 256, 0, stream>>>(
        Aqb, Akb, Avb, Wqb, Wkb, Wvb, bq, bk, bv, Qb, Kb, Vtb);

    attn_mfma<<<dim3(SEQ / 128, BATCH * NHEAD), 256, 0, stream>>>(
        Qb, Kb, Vtb, mask, Hb);

    gemm_out<<<dim3(MROWS / 128, D_MODEL / 128), 256, 0, stream>>>(
        Hb, Wob, bo, out);
}

// Round 6
// 344.530 us; speedup vs baseline: 1.0752x; 1.0752x over previous
//
#include <hip/hip_runtime.h>
#include <hip/hip_bf16.h>
#include <cstdint>
#include <cstddef>

#define D_MODEL 1024
#define SEQ     2048
#define BATCH   4
#define NHEAD   16
#define HD      64
#define MROWS   (BATCH * SEQ)   // 8192

typedef __attribute__((ext_vector_type(8))) short  short8;    // 8 bf16 (4 VGPRs)
typedef __attribute__((ext_vector_type(4))) float  floatx4;   // MFMA acc
typedef __attribute__((ext_vector_type(4))) unsigned short ushort4v; // 8B pack
typedef unsigned short u16;

__device__ __forceinline__ u16 f2bf(float x) {
    __hip_bfloat16 h = __float2bfloat16(x);
    return *(u16*)&h;
}

// async global->LDS, 16B per lane. LDS dest = wave-uniform base + lane*16.
__device__ __forceinline__ void async_copy16(const u16* g, u16* l) {
    __builtin_amdgcn_global_load_lds(
        (const __attribute__((address_space(1))) void*)g,
        (__attribute__((address_space(3))) void*)l, 16, 0, 0);
}

// ---------------------------------------------------------------------------
// fp32 -> bf16 converts: 4 weight tensors (1M elems) + 3 activation tensors
// (8.39M elems). 8 elems/thread, grid.y selects tensor, early-exit past n.
// ---------------------------------------------------------------------------
__device__ __forceinline__ void cvt8(const float* s, u16* d, size_t i) {
    const float4 a = *(const float4*)(s + i);
    const float4 b = *(const float4*)(s + i + 4);
    short8 o;
    o[0] = (short)f2bf(a.x); o[1] = (short)f2bf(a.y);
    o[2] = (short)f2bf(a.z); o[3] = (short)f2bf(a.w);
    o[4] = (short)f2bf(b.x); o[5] = (short)f2bf(b.y);
    o[6] = (short)f2bf(b.z); o[7] = (short)f2bf(b.w);
    *(short8*)(d + i) = o;
}

__global__ __launch_bounds__(256) void cvt7(
    const float* __restrict__ s0, const float* __restrict__ s1,
    const float* __restrict__ s2, const float* __restrict__ s3,
    const float* __restrict__ s4, const float* __restrict__ s5,
    const float* __restrict__ s6,
    u16* __restrict__ d0, u16* __restrict__ d1,
    u16* __restrict__ d2, u16* __restrict__ d3,
    u16* __restrict__ d4, u16* __restrict__ d5,
    u16* __restrict__ d6)
{
    const int y = blockIdx.y;
    const float* s;
    u16* d;
    size_t n;
    switch (y) {
        case 0: s = s0; d = d0; n = (size_t)D_MODEL * D_MODEL; break;
        case 1: s = s1; d = d1; n = (size_t)D_MODEL * D_MODEL; break;
        case 2: s = s2; d = d2; n = (size_t)D_MODEL * D_MODEL; break;
        case 3: s = s3; d = d3; n = (size_t)D_MODEL * D_MODEL; break;
        case 4: s = s4; d = d4; n = (size_t)MROWS * D_MODEL;   break;
        case 5: s = s5; d = d5; n = (size_t)MROWS * D_MODEL;   break;
        default: s = s6; d = d6; n = (size_t)MROWS * D_MODEL;  break;
    }
    const size_t i = ((size_t)blockIdx.x * 256 + threadIdx.x) * 8;
    if (i < n) cvt8(s, d, i);
}

// ---------------------------------------------------------------------------
// Fused QKV GEMM, pure bf16, DOUBLE-BUFFERED LDS (T3 minimum-2-phase):
//   prologue stages tile 0 into buf0; each iteration: barrier (drains the
//   in-flight stage into buf cur), issue stage(t+1 -> buf cur^1), compute(t)
//   from buf cur. The vmcnt(0) drain at the next barrier then sits AFTER a
//   full compute phase instead of immediately after issue (R5 structure was
//   1-phase: stage; barrier; compute -> zero in-block overlap at 2 blk/CU).
// Epilogues: exact R3 versions (scalar Q/K stores — the R5 LDS re-layout
// regressed ~+17 µs; V via LDS transpose).
// z=0,1 (Q,K): out bf16 [B,H,S,Hd].  z=2 (V): out bf16 [B,H,Hd,S].
// 128x128 tile, BK=64, 256 thr = 4 waves, 4x4 MFMA/wave. LDS 64 KB.
// ---------------------------------------------------------------------------
__global__ __launch_bounds__(256) void gemm_qkv(
    const u16* __restrict__ Aq, const u16* __restrict__ Ak,
    const u16* __restrict__ Av,
    const u16* __restrict__ Wqp, const u16* __restrict__ Wkp,
    const u16* __restrict__ Wvp,
    const float* __restrict__ bqp, const float* __restrict__ bkp,
    const float* __restrict__ bvp,
    u16* __restrict__ oq, u16* __restrict__ ok, u16* __restrict__ ov)
{
    constexpr int K = D_MODEL;
    __shared__ __align__(16) u16 smem[32768];   // 64 KB = 2 x (As 16K + Ws 16K)

    const int z = blockIdx.z;
    const u16*   A    = z == 0 ? Aq  : (z == 1 ? Ak  : Av);
    const u16*   W    = z == 0 ? Wqp : (z == 1 ? Wkp : Wvp);
    const float* bias = z == 0 ? bqp : (z == 1 ? bkp : bvp);
    u16*         out  = z == 0 ? oq  : (z == 1 ? ok  : ov);

    const int bm = blockIdx.x * 128;
    const int bn = blockIdx.y * 128;
    const int t  = threadIdx.x;
    const int w  = t >> 6;
    const int l  = t & 63;
    const int li = l & 15;
    const int quad = l >> 4;
    const int wm = (w & 1) * 64;
    const int wn = (w >> 1) * 64;
    const int lrow = l >> 3;
    const int lcol = (l & 7) * 8;

    const u16* Ag = A + (size_t)bm * K;
    const u16* Wg = W + (size_t)bn * K;

    floatx4 acc[4][4];
    #pragma unroll
    for (int mi = 0; mi < 4; mi++)
        #pragma unroll
        for (int ni = 0; ni < 4; ni++) acc[mi][ni] = (floatx4){0.f,0.f,0.f,0.f};

    // prologue: stage tile 0 into buf 0
    #pragma unroll
    for (int j = 0; j < 4; j++) {
        const int r = w * 32 + j * 8;
        async_copy16(Ag + (size_t)(r + lrow) * K + lcol, smem + r * 64);
        async_copy16(Wg + (size_t)(r + lrow) * K + lcol, smem + 8192 + r * 64);
    }

    int cur = 0;
    for (int kt = 0; kt < K; kt += 64) {
        __syncthreads();   // vmcnt(0) drain: stage(kt) -> buf cur complete

        if (kt + 64 < K) {   // stage(t+1) -> buf cur^1, flies over compute(t)
            u16* Asn = smem + (cur ^ 1) * 16384;
            u16* Wsn = Asn + 8192;
            #pragma unroll
            for (int j = 0; j < 4; j++) {
                const int r = w * 32 + j * 8;
                async_copy16(Ag + (size_t)(r + lrow) * K + kt + 64 + lcol, Asn + r * 64);
                async_copy16(Wg + (size_t)(r + lrow) * K + kt + 64 + lcol, Wsn + r * 64);
            }
        }

        const u16* Asc = smem + cur * 16384;
        const u16* Wsc = Asc + 8192;
        #pragma unroll
        for (int ks = 0; ks < 2; ks++) {
            short8 af[4], bf[4];
            #pragma unroll
            for (int i = 0; i < 4; i++) {
                af[i] = *(const short8*)&Asc[(wm + i * 16 + li) * 64 + ks * 32 + quad * 8];
                bf[i] = *(const short8*)&Wsc[(wn + i * 16 + li) * 64 + ks * 32 + quad * 8];
            }
            #pragma unroll
            for (int mi = 0; mi < 4; mi++)
                #pragma unroll
                for (int ni = 0; ni < 4; ni++)
                    acc[mi][ni] = __builtin_amdgcn_mfma_f32_16x16x32_bf16(
                        af[mi], bf[ni], acc[mi][ni], 0, 0, 0);
        }
        cur ^= 1;
    }

    if (z < 2) {   // [B,H,S,Hd] — R3 scalar epilogue
        #pragma unroll
        for (int mi = 0; mi < 4; mi++)
            #pragma unroll
            for (int ni = 0; ni < 4; ni++) {
                const int c  = bn + wn + ni * 16 + li;
                const int h  = c >> 6;
                const int hd = c & 63;
                const float bz = bias[c];
                #pragma unroll
                for (int reg = 0; reg < 4; reg++) {
                    const int r = bm + wm + mi * 16 + quad * 4 + reg;
                    const int b = r >> 11;
                    const int s = r & (SEQ - 1);
                    out[(((size_t)(b * NHEAD + h) * SEQ) + s) * HD + hd] = f2bf(acc[mi][ni][reg] + bz);
                }
            }
    } else {       // V: transpose tile in LDS, store [B,H,Hd,S]
        u16 (*Ct)[128] = (u16(*)[128])smem;
        __syncthreads();
        #pragma unroll
        for (int mi = 0; mi < 4; mi++)
            #pragma unroll
            for (int ni = 0; ni < 4; ni++) {
                const int cl = wn + ni * 16 + li;
                const float bz = bias[bn + cl];
                #pragma unroll
                for (int reg = 0; reg < 4; reg++) {
                    const int rl = wm + mi * 16 + quad * 4 + reg;
                    Ct[cl][rl] = f2bf(acc[mi][ni][reg] + bz);
                }
            }
        __syncthreads();
        const int cl   = t >> 1;
        const int half = t & 1;
        const int cg = bn + cl;
        const int h  = cg >> 6;
        const int hd = cg & 63;
        const int b  = bm >> 11;
        const int s0 = (bm & (SEQ - 1)) + half * 64;
        u16* dst = out + (((size_t)(b * NHEAD + h) * HD) + hd) * SEQ + s0;
        const short8* sp = (const short8*)&Ct[cl][half * 64];
        #pragma unroll
        for (int i = 0; i < 8; i++) ((short8*)dst)[i] = sp[i];
    }
}

// ---------------------------------------------------------------------------
// Output projection: out = H @ Wo^T + bo, fp32 out. H bf16, Wo bf16.
// Same T3 minimum-2-phase double-buffer as gemm_qkv.
// ---------------------------------------------------------------------------
__global__ __launch_bounds__(256) void gemm_out(
    const u16* __restrict__ A,
    const u16* __restrict__ W,
    const float* __restrict__ bias,
    float* __restrict__ out)
{
    constexpr int K = D_MODEL;
    __shared__ __align__(16) u16 smem[32768];   // 64 KB double buffer

    const int bm = blockIdx.x * 128;
    const int bn = blockIdx.y * 128;
    const int t  = threadIdx.x;
    const int w  = t >> 6;
    const int l  = t & 63;
    const int li = l & 15;
    const int quad = l >> 4;
    const int wm = (w & 1) * 64;
    const int wn = (w >> 1) * 64;
    const int lrow = l >> 3;
    const int lcol = (l & 7) * 8;

    const u16* Ag = A + (size_t)bm * K;
    const u16* Wg = W + (size_t)bn * K;

    floatx4 acc[4][4];
    #pragma unroll
    for (int mi = 0; mi < 4; mi++)
        #pragma unroll
        for (int ni = 0; ni < 4; ni++) acc[mi][ni] = (floatx4){0.f,0.f,0.f,0.f};

    // prologue: stage tile 0 into buf 0
    #pragma unroll
    for (int j = 0; j < 4; j++) {
        const int r = w * 32 + j * 8;
        async_copy16(Ag + (size_t)(r + lrow) * K + lcol, smem + r * 64);
        async_copy16(Wg + (size_t)(r + lrow) * K + lcol, smem + 8192 + r * 64);
    }

    int cur = 0;
    for (int kt = 0; kt < K; kt += 64) {
        __syncthreads();

        if (kt + 64 < K) {
            u16* Asn = smem + (cur ^ 1) * 16384;
            u16* Wsn = Asn + 8192;
            #pragma unroll
            for (int j = 0; j < 4; j++) {
                const int r = w * 32 + j * 8;
                async_copy16(Ag + (size_t)(r + lrow) * K + kt + 64 + lcol, Asn + r * 64);
                async_copy16(Wg + (size_t)(r + lrow) * K + kt + 64 + lcol, Wsn + r * 64);
            }
        }

        const u16* Asc = smem + cur * 16384;
        const u16* Wsc = Asc + 8192;
        #pragma unroll
        for (int ks = 0; ks < 2; ks++) {
            short8 af[4], bf[4];
            #pragma unroll
            for (int i = 0; i < 4; i++) {
                af[i] = *(const short8*)&Asc[(wm + i * 16 + li) * 64 + ks * 32 + quad * 8];
                bf[i] = *(const short8*)&Wsc[(wn + i * 16 + li) * 64 + ks * 32 + quad * 8];
            }
            #pragma unroll
            for (int mi = 0; mi < 4; mi++)
                #pragma unroll
                for (int ni = 0; ni < 4; ni++)
                    acc[mi][ni] = __builtin_amdgcn_mfma_f32_16x16x32_bf16(
                        af[mi], bf[ni], acc[mi][ni], 0, 0, 0);
        }
        cur ^= 1;
    }

    #pragma unroll
    for (int mi = 0; mi < 4; mi++)
        #pragma unroll
        for (int ni = 0; ni < 4; ni++) {
            const int c = bn + wn + ni * 16 + li;
            const float bz = bias[c];
            #pragma unroll
            for (int reg = 0; reg < 4; reg++) {
                const int r = bm + wm + mi * 16 + quad * 4 + reg;
                out[(size_t)r * D_MODEL + c] = acc[mi][ni][reg] + bz;
            }
        }
}

// ---------------------------------------------------------------------------
// Flash attention v6 (R3 exact — best measured: 97.1 µs).
//   Register diet (per-kb fused softmax, sacc live = 8 regs) +
//   __launch_bounds__(256,4) + 2-barrier single-buffer schedule:
//     β1: Ks(t)+mc(t) ready -> stage V(t); QK^T+softmax over the drain.
//     β2: V(t) drained    -> stage K(t+1)+mc(t+1); PV over the drain.
// S^T = K Q^T; p = exp2(s*CSCALE + mc); packed b64 P writes; XOR-swizzled
// K/V LDS. LDS = 8 + 8 + 18 + 0.25 KB = ~35KB.
// ---------------------------------------------------------------------------
#define LOG2E   1.44269504088896340736f
#define CSCALE  (0.125f * LOG2E)        // 1/sqrt(64) * log2(e)

__global__ __launch_bounds__(256, 4) void attn_mfma(
    const u16* __restrict__ Q,
    const u16* __restrict__ K,
    const u16* __restrict__ Vt,
    const int* __restrict__ mask,
    u16* __restrict__ H)
{
    __shared__ __align__(16) u16 Ks[64 * 64];     // 8 KB  [key][hd], swizzled
    __shared__ __align__(16) u16 Vs[64 * 64];     // 8 KB  [hd][key], swizzled
    __shared__ __align__(16) u16 Ps[4][32][72];   // 18 KB per-wave P [qrow][key]
    __shared__ __align__(16) float mc[64];        // 256 B mask bias

    const int bh  = blockIdx.y;
    const int b   = bh >> 4;
    const int h   = bh & 15;
    const int q0  = blockIdx.x * 128;
    const int t   = threadIdx.x;
    const int w   = t >> 6;
    const int l   = t & 63;
    const int li  = l & 15;
    const int quad  = l >> 4;
    const int lrow8 = l >> 3;
    const int gch   = (l & 7) ^ lrow8;   // XOR-swizzled global chunk
    const int swz   = li & 7;            // frag-read swizzle term

    short8 qf[2][2];
    #pragma unroll
    for (int qb = 0; qb < 2; qb++) {
        const u16* Qrow = Q + ((size_t)bh * SEQ + q0 + w * 32 + qb * 16 + li) * HD;
        qf[qb][0] = *(const short8*)(Qrow + quad * 8);
        qf[qb][1] = *(const short8*)(Qrow + 32 + quad * 8);
    }

    const u16* Kbh = K  + (size_t)bh * SEQ * HD;
    const u16* Vbh = Vt + (size_t)bh * HD * SEQ;
    const int* mg  = mask + (size_t)b * SEQ;

    floatx4 oacc[4][2];
    #pragma unroll
    for (int hm = 0; hm < 4; hm++)
        #pragma unroll
        for (int qb = 0; qb < 2; qb++) oacc[hm][qb] = (floatx4){0.f,0.f,0.f,0.f};
    float rs[2] = {0.f, 0.f};

    // prologue: stage K(0) + mc(0); drained by the first loop-top barrier
    #pragma unroll
    for (int j = 0; j < 2; j++) {
        const int rb = w * 16 + j * 8;
        async_copy16(Kbh + (size_t)(rb + lrow8) * HD + gch * 8, &Ks[rb * 64]);
    }
    if (t < 64) mc[t] = (mg[t] != 0) ? -16.0f : -1.0e9f;

    for (int kt = 0; kt < SEQ; kt += 64) {
        __syncthreads();   // β1: Ks(t)+mc(t) published; Vs free (PV(t-1) done)

        // stage V(t): drains at β2, overlapping QK^T + softmax
        #pragma unroll
        for (int j = 0; j < 2; j++) {
            const int rb = w * 16 + j * 8;
            async_copy16(Vbh + (size_t)(rb + lrow8) * SEQ + kt + gch * 8,
                         &Vs[rb * 64]);
        }

        // ---- S^T = K Q^T, softmax fused per kb (sacc live = 8 regs) -----
        #pragma unroll
        for (int kb = 0; kb < 4; kb++) {
            floatx4 s0 = (floatx4){0.f,0.f,0.f,0.f};
            floatx4 s1 = (floatx4){0.f,0.f,0.f,0.f};
            #pragma unroll
            for (int ks = 0; ks < 2; ks++) {
                const short8 kf = *(const short8*)
                    &Ks[(kb * 16 + li) * 64 + ((ks * 4 + quad) ^ swz) * 8];
                __builtin_amdgcn_s_setprio(1);
                s0 = __builtin_amdgcn_mfma_f32_16x16x32_bf16(kf, qf[0][ks], s0, 0, 0, 0);
                s1 = __builtin_amdgcn_mfma_f32_16x16x32_bf16(kf, qf[1][ks], s1, 0, 0, 0);
                __builtin_amdgcn_s_setprio(0);
            }
            const float4 m4 = *(const float4*)&mc[kb * 16 + quad * 4];
            {
                const float p0 = __builtin_amdgcn_exp2f(fmaf(s0[0], CSCALE, m4.x));
                const float p1 = __builtin_amdgcn_exp2f(fmaf(s0[1], CSCALE, m4.y));
                const float p2 = __builtin_amdgcn_exp2f(fmaf(s0[2], CSCALE, m4.z));
                const float p3 = __builtin_amdgcn_exp2f(fmaf(s0[3], CSCALE, m4.w));
                rs[0] += (p0 + p1) + (p2 + p3);
                ushort4v pk;
                pk[0] = f2bf(p0); pk[1] = f2bf(p1);
                pk[2] = f2bf(p2); pk[3] = f2bf(p3);
                *(ushort4v*)&Ps[w][li][kb * 16 + quad * 4] = pk;
            }
            {
                const float p0 = __builtin_amdgcn_exp2f(fmaf(s1[0], CSCALE, m4.x));
                const float p1 = __builtin_amdgcn_exp2f(fmaf(s1[1], CSCALE, m4.y));
                const float p2 = __builtin_amdgcn_exp2f(fmaf(s1[2], CSCALE, m4.z));
                const float p3 = __builtin_amdgcn_exp2f(fmaf(s1[3], CSCALE, m4.w));
                rs[1] += (p0 + p1) + (p2 + p3);
                ushort4v pk;
                pk[0] = f2bf(p0); pk[1] = f2bf(p1);
                pk[2] = f2bf(p2); pk[3] = f2bf(p3);
                *(ushort4v*)&Ps[w][16 + li][kb * 16 + quad * 4] = pk;
            }
        }

        __syncthreads();   // β2: V(t) drained; all waves done with Ks(t)/mc(t)

        if (kt + 64 < SEQ) {
            // stage K(t+1) + mc(t+1): drains at β1(t+1), overlapping PV
            #pragma unroll
            for (int j = 0; j < 2; j++) {
                const int rb = w * 16 + j * 8;
                async_copy16(Kbh + (size_t)(kt + 64 + rb + lrow8) * HD + gch * 8,
                             &Ks[rb * 64]);
            }
            if (t < 64) mc[t] = (mg[kt + 64 + t] != 0) ? -16.0f : -1.0e9f;
        }

        // ---- O^T += V^T P^T ---------------------------------------------
        #pragma unroll
        for (int ks = 0; ks < 2; ks++) {
            short8 pf[2];
            #pragma unroll
            for (int qb = 0; qb < 2; qb++)
                pf[qb] = *(const short8*)&Ps[w][qb * 16 + li][ks * 32 + quad * 8];
            __builtin_amdgcn_s_setprio(1);
            #pragma unroll
            for (int hm = 0; hm < 4; hm++) {
                const short8 vf = *(const short8*)&Vs[(hm * 16 + li) * 64 + ((ks * 4 + quad) ^ swz) * 8];
                #pragma unroll
                for (int qb = 0; qb < 2; qb++)
                    oacc[hm][qb] = __builtin_amdgcn_mfma_f32_16x16x32_bf16(
                        vf, pf[qb], oacc[hm][qb], 0, 0, 0);
            }
            __builtin_amdgcn_s_setprio(0);
        }
    }

    float linv[2];
    #pragma unroll
    for (int qb = 0; qb < 2; qb++) {
        float v = rs[qb];
        v += __shfl_xor(v, 16, 64);
        v += __shfl_xor(v, 32, 64);
        linv[qb] = 1.0f / v;
    }
    #pragma unroll
    for (int qb = 0; qb < 2; qb++) {
        const size_t row = (size_t)b * SEQ + q0 + w * 32 + qb * 16 + li;
        #pragma unroll
        for (int hm = 0; hm < 4; hm++) {
            ushort4v o;
            #pragma unroll
            for (int reg = 0; reg < 4; reg++)
                o[reg] = f2bf(oacc[hm][qb][reg] * linv[qb]);
            *(ushort4v*)&H[row * D_MODEL + h * 64 + hm * 16 + quad * 4] = o;
        }
    }
}

// ---------------------------------------------------------------------------
extern "C" void kernel_launch(void* const* d_in, const int* in_sizes, int n_in,
                              void* d_out, int out_size, void* d_ws, size_t ws_size,
                              hipStream_t stream)
{
    const float* query = (const float*)d_in[0];
    const float* key_  = (const float*)d_in[1];
    const float* value = (const float*)d_in[2];
    const int*   mask  = (const int*)  d_in[3];
    const float* Wq = (const float*)d_in[4];
    const float* bq = (const float*)d_in[5];
    const float* Wk = (const float*)d_in[6];
    const float* bk = (const float*)d_in[7];
    const float* Wv = (const float*)d_in[8];
    const float* bv = (const float*)d_in[9];
    const float* Wo = (const float*)d_in[10];
    const float* bo = (const float*)d_in[11];
    float* out = (float*)d_out;

    const size_t per = (size_t)BATCH * NHEAD * SEQ * HD;   // 8,388,608 elems
    const size_t wsz = (size_t)D_MODEL * D_MODEL;          // 1,048,576 elems
    u16* Qb  = (u16*)d_ws;          // projected Q [B,H,S,Hd]        16 MB
    u16* Kb  = Qb  + per;           // projected K [B,H,S,Hd]        16 MB
    u16* Vtb = Kb  + per;           // projected V^T [B,H,Hd,S]      16 MB
    u16* Wqb = Vtb + per;           // bf16 weights                   2 MB x4
    u16* Wkb = Wqb + wsz;
    u16* Wvb = Wkb + wsz;
    u16* Wob = Wvb + wsz;
    u16* Aqb = Wob + wsz;           // bf16 activations              16 MB x3
    u16* Akb = Aqb + per;
    u16* Avb = Akb + per;
    u16* Hb  = Aqb;                 // attention out: ALIASES Aqb (dead after
                                    // gemm_qkv).  Total ~104 MB.

    // 7-tensor fp32->bf16 convert: weights (y=0..3) + activations (y=4..6)
    cvt7<<<dim3((per / 8 + 255) / 256, 7), 256, 0, stream>>>(
        Wq, Wk, Wv, Wo, query, key_, value,
        Wqb, Wkb, Wvb, Wob, Aqb, Akb, Avb);

    gemm_qkv<<<dim3(MROWS / 128, D_MODEL / 128, 3), 256, 0, stream>>>(
        Aqb, Akb, Avb, Wqb, Wkb, Wvb, bq, bk, bv, Qb, Kb, Vtb);

    attn_mfma<<<dim3(SEQ / 128, BATCH * NHEAD), 256, 0, stream>>>(
        Qb, Kb, Vtb, mask, Hb);

    gemm_out<<<dim3(MROWS / 128, D_MODEL / 128), 256, 0, stream>>>(
        Hb, Wob, bo, out);
}

// Round 7
// 340.731 us; speedup vs baseline: 1.0872x; 1.0111x over previous
//
#include <hip/hip_runtime.h>
#include <hip/hip_bf16.h>
#include <cstdint>
#include <cstddef>

#define D_MODEL 1024
#define SEQ     2048
#define BATCH   4
#define NHEAD   16
#define HD      64
#define MROWS   (BATCH * SEQ)   // 8192

typedef __attribute__((ext_vector_type(8))) short  short8;    // 8 bf16 (4 VGPRs)
typedef __attribute__((ext_vector_type(4))) float  floatx4;   // MFMA acc
typedef __attribute__((ext_vector_type(4))) unsigned short ushort4v; // 8B pack
typedef unsigned short u16;

__device__ __forceinline__ u16 f2bf(float x) {
    __hip_bfloat16 h = __float2bfloat16(x);
    return *(u16*)&h;
}

// async global->LDS, 16B per lane. LDS dest = wave-uniform base + lane*16.
__device__ __forceinline__ void async_copy16(const u16* g, u16* l) {
    __builtin_amdgcn_global_load_lds(
        (const __attribute__((address_space(1))) void*)g,
        (__attribute__((address_space(3))) void*)l, 16, 0, 0);
}

// ---------------------------------------------------------------------------
// fp32 -> bf16 weight converts (4 tensors, 1M elems each). Activations are
// now converted INSIDE gemm_qkv (T14 reg-staged 2-phase) — the separate
// 144 MB activation pass (~23 µs pure HBM overhead) is gone.
// ---------------------------------------------------------------------------
__device__ __forceinline__ void cvt8(const float* s, u16* d, size_t i) {
    const float4 a = *(const float4*)(s + i);
    const float4 b = *(const float4*)(s + i + 4);
    short8 o;
    o[0] = (short)f2bf(a.x); o[1] = (short)f2bf(a.y);
    o[2] = (short)f2bf(a.z); o[3] = (short)f2bf(a.w);
    o[4] = (short)f2bf(b.x); o[5] = (short)f2bf(b.y);
    o[6] = (short)f2bf(b.z); o[7] = (short)f2bf(b.w);
    *(short8*)(d + i) = o;
}

__global__ __launch_bounds__(256) void cvt4(
    const float* __restrict__ s0, const float* __restrict__ s1,
    const float* __restrict__ s2, const float* __restrict__ s3,
    u16* __restrict__ d0, u16* __restrict__ d1,
    u16* __restrict__ d2, u16* __restrict__ d3)
{
    const float* s = blockIdx.y == 0 ? s0 : (blockIdx.y == 1 ? s1 :
                     (blockIdx.y == 2 ? s2 : s3));
    u16*         d = blockIdx.y == 0 ? d0 : (blockIdx.y == 1 ? d1 :
                     (blockIdx.y == 2 ? d2 : d3));
    cvt8(s, d, ((size_t)blockIdx.x * 256 + threadIdx.x) * 8);
}

// ---------------------------------------------------------------------------
// Fused QKV GEMM: A = fp32 activations read DIRECTLY (no cvt pass).
// T14 reg-staged 2-phase for A + gload_lds 2-phase for W:
//   barrier(t): [A ds_writes(t) done pre-barrier; W gload(t) drained vmcnt0]
//   -> issue A fp32 reg-loads(t+1) FIRST (pa-wait = vmcnt(8), W's keep
//      flying), then W gload_lds(t+1) -> buf^1
//   -> compute(t) from buf cur (loads fly over it)
//   -> convert pa -> bf16, ds_write -> buf^1 (issue-early / write-late)
// R0's version of this idea was 1-phase (convert serialized between
// barriers, 426 TF); the 2-phase overlap is what makes reg-staging pay.
// Epilogues: R3 scalar Q/K stores; V via LDS transpose (proven).
// z=0,1 (Q,K): out bf16 [B,H,S,Hd].  z=2 (V): out bf16 [B,H,Hd,S].
// 128x128 tile, BK=64, 256 thr = 4 waves, 4x4 MFMA/wave. LDS 64 KB.
// ---------------------------------------------------------------------------
__global__ __launch_bounds__(256) void gemm_qkv(
    const float* __restrict__ Aq, const float* __restrict__ Ak,
    const float* __restrict__ Av,
    const u16* __restrict__ Wqp, const u16* __restrict__ Wkp,
    const u16* __restrict__ Wvp,
    const float* __restrict__ bqp, const float* __restrict__ bkp,
    const float* __restrict__ bvp,
    u16* __restrict__ oq, u16* __restrict__ ok, u16* __restrict__ ov)
{
    constexpr int K = D_MODEL;
    __shared__ __align__(16) u16 smem[32768];   // 64 KB = 2 x (As 16K + Ws 16K)

    const int z = blockIdx.z;
    const float* A    = z == 0 ? Aq  : (z == 1 ? Ak  : Av);
    const u16*   W    = z == 0 ? Wqp : (z == 1 ? Wkp : Wvp);
    const float* bias = z == 0 ? bqp : (z == 1 ? bkp : bvp);
    u16*         out  = z == 0 ? oq  : (z == 1 ? ok  : ov);

    const int bm = blockIdx.x * 128;
    const int bn = blockIdx.y * 128;
    const int t  = threadIdx.x;
    const int w  = t >> 6;
    const int l  = t & 63;
    const int li = l & 15;
    const int quad = l >> 4;
    const int wm = (w & 1) * 64;
    const int wn = (w >> 1) * 64;
    const int lrow = l >> 3;
    const int lcol = (l & 7) * 8;
    const int srow = w * 32 + (l >> 3);   // A staging row (+ j*8)
    const int lc8  = (l & 7) * 8;         // A staging col offset (elems)

    const float* Ab = A + (size_t)bm * K;
    const u16*   Wg = W + (size_t)bn * K;

    float4 pa[4][2];   // in-flight A fp32 (32 VGPR)

    floatx4 acc[4][4];
    #pragma unroll
    for (int mi = 0; mi < 4; mi++)
        #pragma unroll
        for (int ni = 0; ni < 4; ni++) acc[mi][ni] = (floatx4){0.f,0.f,0.f,0.f};

    // prologue: A(0) reg-loads, W(0) gload -> buf0, convert+write A(0)
    #pragma unroll
    for (int j = 0; j < 4; j++) {
        const float* ap = Ab + (size_t)(srow + j * 8) * K + lc8;
        pa[j][0] = *(const float4*)ap;
        pa[j][1] = *(const float4*)(ap + 4);
    }
    #pragma unroll
    for (int j = 0; j < 4; j++) {
        const int r = w * 32 + j * 8;
        async_copy16(Wg + (size_t)(r + lrow) * K + lcol, smem + 8192 + r * 64);
    }
    #pragma unroll
    for (int j = 0; j < 4; j++) {
        short8 av;
        av[0] = (short)f2bf(pa[j][0].x); av[1] = (short)f2bf(pa[j][0].y);
        av[2] = (short)f2bf(pa[j][0].z); av[3] = (short)f2bf(pa[j][0].w);
        av[4] = (short)f2bf(pa[j][1].x); av[5] = (short)f2bf(pa[j][1].y);
        av[6] = (short)f2bf(pa[j][1].z); av[7] = (short)f2bf(pa[j][1].w);
        *(short8*)&smem[(srow + j * 8) * 64 + lc8] = av;
    }

    int cur = 0;
    for (int kt = 0; kt < K; kt += 64) {
        __syncthreads();   // A ds_writes(t) + W gload(t) complete in buf cur

        const bool pf = (kt + 64 < K);
        if (pf) {
            // A reg-loads(t+1) FIRST: pa-wait later = vmcnt(8), W's fly on
            #pragma unroll
            for (int j = 0; j < 4; j++) {
                const float* ap = Ab + (size_t)(srow + j * 8) * K + kt + 64 + lc8;
                pa[j][0] = *(const float4*)ap;
                pa[j][1] = *(const float4*)(ap + 4);
            }
            u16* Wsn = smem + (cur ^ 1) * 16384 + 8192;
            #pragma unroll
            for (int j = 0; j < 4; j++) {
                const int r = w * 32 + j * 8;
                async_copy16(Wg + (size_t)(r + lrow) * K + kt + 64 + lcol, Wsn + r * 64);
            }
        }

        const u16* Asc = smem + cur * 16384;
        const u16* Wsc = Asc + 8192;
        #pragma unroll
        for (int ks = 0; ks < 2; ks++) {
            short8 af[4], bf[4];
            #pragma unroll
            for (int i = 0; i < 4; i++) {
                af[i] = *(const short8*)&Asc[(wm + i * 16 + li) * 64 + ks * 32 + quad * 8];
                bf[i] = *(const short8*)&Wsc[(wn + i * 16 + li) * 64 + ks * 32 + quad * 8];
            }
            #pragma unroll
            for (int mi = 0; mi < 4; mi++)
                #pragma unroll
                for (int ni = 0; ni < 4; ni++)
                    acc[mi][ni] = __builtin_amdgcn_mfma_f32_16x16x32_bf16(
                        af[mi], bf[ni], acc[mi][ni], 0, 0, 0);
        }

        if (pf) {   // write-late: convert A(t+1) -> buf^1 (pre-barrier)
            u16* Asn = smem + (cur ^ 1) * 16384;
            #pragma unroll
            for (int j = 0; j < 4; j++) {
                short8 av;
                av[0] = (short)f2bf(pa[j][0].x); av[1] = (short)f2bf(pa[j][0].y);
                av[2] = (short)f2bf(pa[j][0].z); av[3] = (short)f2bf(pa[j][0].w);
                av[4] = (short)f2bf(pa[j][1].x); av[5] = (short)f2bf(pa[j][1].y);
                av[6] = (short)f2bf(pa[j][1].z); av[7] = (short)f2bf(pa[j][1].w);
                *(short8*)&Asn[(srow + j * 8) * 64 + lc8] = av;
            }
        }
        cur ^= 1;
    }

    if (z < 2) {   // [B,H,S,Hd] — R3 scalar epilogue
        #pragma unroll
        for (int mi = 0; mi < 4; mi++)
            #pragma unroll
            for (int ni = 0; ni < 4; ni++) {
                const int c  = bn + wn + ni * 16 + li;
                const int h  = c >> 6;
                const int hd = c & 63;
                const float bz = bias[c];
                #pragma unroll
                for (int reg = 0; reg < 4; reg++) {
                    const int r = bm + wm + mi * 16 + quad * 4 + reg;
                    const int b = r >> 11;
                    const int s = r & (SEQ - 1);
                    out[(((size_t)(b * NHEAD + h) * SEQ) + s) * HD + hd] = f2bf(acc[mi][ni][reg] + bz);
                }
            }
    } else {       // V: transpose tile in LDS, store [B,H,Hd,S]
        u16 (*Ct)[128] = (u16(*)[128])smem;
        __syncthreads();
        #pragma unroll
        for (int mi = 0; mi < 4; mi++)
            #pragma unroll
            for (int ni = 0; ni < 4; ni++) {
                const int cl = wn + ni * 16 + li;
                const float bz = bias[bn + cl];
                #pragma unroll
                for (int reg = 0; reg < 4; reg++) {
                    const int rl = wm + mi * 16 + quad * 4 + reg;
                    Ct[cl][rl] = f2bf(acc[mi][ni][reg] + bz);
                }
            }
        __syncthreads();
        const int cl   = t >> 1;
        const int half = t & 1;
        const int cg = bn + cl;
        const int h  = cg >> 6;
        const int hd = cg & 63;
        const int b  = bm >> 11;
        const int s0 = (bm & (SEQ - 1)) + half * 64;
        u16* dst = out + (((size_t)(b * NHEAD + h) * HD) + hd) * SEQ + s0;
        const short8* sp = (const short8*)&Ct[cl][half * 64];
        #pragma unroll
        for (int i = 0; i < 8; i++) ((short8*)dst)[i] = sp[i];
    }
}

// ---------------------------------------------------------------------------
// Output projection: out = H @ Wo^T + bo, fp32 out. H bf16, Wo bf16.
// T3 minimum-2-phase double-buffer (R6, unchanged).
// ---------------------------------------------------------------------------
__global__ __launch_bounds__(256) void gemm_out(
    const u16* __restrict__ A,
    const u16* __restrict__ W,
    const float* __restrict__ bias,
    float* __restrict__ out)
{
    constexpr int K = D_MODEL;
    __shared__ __align__(16) u16 smem[32768];   // 64 KB double buffer

    const int bm = blockIdx.x * 128;
    const int bn = blockIdx.y * 128;
    const int t  = threadIdx.x;
    const int w  = t >> 6;
    const int l  = t & 63;
    const int li = l & 15;
    const int quad = l >> 4;
    const int wm = (w & 1) * 64;
    const int wn = (w >> 1) * 64;
    const int lrow = l >> 3;
    const int lcol = (l & 7) * 8;

    const u16* Ag = A + (size_t)bm * K;
    const u16* Wg = W + (size_t)bn * K;

    floatx4 acc[4][4];
    #pragma unroll
    for (int mi = 0; mi < 4; mi++)
        #pragma unroll
        for (int ni = 0; ni < 4; ni++) acc[mi][ni] = (floatx4){0.f,0.f,0.f,0.f};

    // prologue: stage tile 0 into buf 0
    #pragma unroll
    for (int j = 0; j < 4; j++) {
        const int r = w * 32 + j * 8;
        async_copy16(Ag + (size_t)(r + lrow) * K + lcol, smem + r * 64);
        async_copy16(Wg + (size_t)(r + lrow) * K + lcol, smem + 8192 + r * 64);
    }

    int cur = 0;
    for (int kt = 0; kt < K; kt += 64) {
        __syncthreads();

        if (kt + 64 < K) {
            u16* Asn = smem + (cur ^ 1) * 16384;
            u16* Wsn = Asn + 8192;
            #pragma unroll
            for (int j = 0; j < 4; j++) {
                const int r = w * 32 + j * 8;
                async_copy16(Ag + (size_t)(r + lrow) * K + kt + 64 + lcol, Asn + r * 64);
                async_copy16(Wg + (size_t)(r + lrow) * K + kt + 64 + lcol, Wsn + r * 64);
            }
        }

        const u16* Asc = smem + cur * 16384;
        const u16* Wsc = Asc + 8192;
        #pragma unroll
        for (int ks = 0; ks < 2; ks++) {
            short8 af[4], bf[4];
            #pragma unroll
            for (int i = 0; i < 4; i++) {
                af[i] = *(const short8*)&Asc[(wm + i * 16 + li) * 64 + ks * 32 + quad * 8];
                bf[i] = *(const short8*)&Wsc[(wn + i * 16 + li) * 64 + ks * 32 + quad * 8];
            }
            #pragma unroll
            for (int mi = 0; mi < 4; mi++)
                #pragma unroll
                for (int ni = 0; ni < 4; ni++)
                    acc[mi][ni] = __builtin_amdgcn_mfma_f32_16x16x32_bf16(
                        af[mi], bf[ni], acc[mi][ni], 0, 0, 0);
        }
        cur ^= 1;
    }

    #pragma unroll
    for (int mi = 0; mi < 4; mi++)
        #pragma unroll
        for (int ni = 0; ni < 4; ni++) {
            const int c = bn + wn + ni * 16 + li;
            const float bz = bias[c];
            #pragma unroll
            for (int reg = 0; reg < 4; reg++) {
                const int r = bm + wm + mi * 16 + quad * 4 + reg;
                out[(size_t)r * D_MODEL + c] = acc[mi][ni][reg] + bz;
            }
        }
}

// ---------------------------------------------------------------------------
// Flash attention v6 (R3/R6 exact — best measured: 97.1 µs). FROZEN.
//   Register diet (per-kb fused softmax, sacc live = 8 regs) +
//   __launch_bounds__(256,4) + 2-barrier single-buffer schedule:
//     β1: Ks(t)+mc(t) ready -> stage V(t); QK^T+softmax over the drain.
//     β2: V(t) drained    -> stage K(t+1)+mc(t+1); PV over the drain.
// S^T = K Q^T; p = exp2(s*CSCALE + mc); packed b64 P writes; XOR-swizzled
// K/V LDS. LDS = 8 + 8 + 18 + 0.25 KB = ~35KB.
// NOTE (R4 evidence): occupancy stays ~3 blocks/CU even at 25 KB LDS —
// LDS squeezing is a dead lever here; do not revisit.
// ---------------------------------------------------------------------------
#define LOG2E   1.44269504088896340736f
#define CSCALE  (0.125f * LOG2E)        // 1/sqrt(64) * log2(e)

__global__ __launch_bounds__(256, 4) void attn_mfma(
    const u16* __restrict__ Q,
    const u16* __restrict__ K,
    const u16* __restrict__ Vt,
    const int* __restrict__ mask,
    u16* __restrict__ H)
{
    __shared__ __align__(16) u16 Ks[64 * 64];     // 8 KB  [key][hd], swizzled
    __shared__ __align__(16) u16 Vs[64 * 64];     // 8 KB  [hd][key], swizzled
    __shared__ __align__(16) u16 Ps[4][32][72];   // 18 KB per-wave P [qrow][key]
    __shared__ __align__(16) float mc[64];        // 256 B mask bias

    const int bh  = blockIdx.y;
    const int b   = bh >> 4;
    const int h   = bh & 15;
    const int q0  = blockIdx.x * 128;
    const int t   = threadIdx.x;
    const int w   = t >> 6;
    const int l   = t & 63;
    const int li  = l & 15;
    const int quad  = l >> 4;
    const int lrow8 = l >> 3;
    const int gch   = (l & 7) ^ lrow8;   // XOR-swizzled global chunk
    const int swz   = li & 7;            // frag-read swizzle term

    short8 qf[2][2];
    #pragma unroll
    for (int qb = 0; qb < 2; qb++) {
        const u16* Qrow = Q + ((size_t)bh * SEQ + q0 + w * 32 + qb * 16 + li) * HD;
        qf[qb][0] = *(const short8*)(Qrow + quad * 8);
        qf[qb][1] = *(const short8*)(Qrow + 32 + quad * 8);
    }

    const u16* Kbh = K  + (size_t)bh * SEQ * HD;
    const u16* Vbh = Vt + (size_t)bh * HD * SEQ;
    const int* mg  = mask + (size_t)b * SEQ;

    floatx4 oacc[4][2];
    #pragma unroll
    for (int hm = 0; hm < 4; hm++)
        #pragma unroll
        for (int qb = 0; qb < 2; qb++) oacc[hm][qb] = (floatx4){0.f,0.f,0.f,0.f};
    float rs[2] = {0.f, 0.f};

    // prologue: stage K(0) + mc(0); drained by the first loop-top barrier
    #pragma unroll
    for (int j = 0; j < 2; j++) {
        const int rb = w * 16 + j * 8;
        async_copy16(Kbh + (size_t)(rb + lrow8) * HD + gch * 8, &Ks[rb * 64]);
    }
    if (t < 64) mc[t] = (mg[t] != 0) ? -16.0f : -1.0e9f;

    for (int kt = 0; kt < SEQ; kt += 64) {
        __syncthreads();   // β1: Ks(t)+mc(t) published; Vs free (PV(t-1) done)

        // stage V(t): drains at β2, overlapping QK^T + softmax
        #pragma unroll
        for (int j = 0; j < 2; j++) {
            const int rb = w * 16 + j * 8;
            async_copy16(Vbh + (size_t)(rb + lrow8) * SEQ + kt + gch * 8,
                         &Vs[rb * 64]);
        }

        // ---- S^T = K Q^T, softmax fused per kb (sacc live = 8 regs) -----
        #pragma unroll
        for (int kb = 0; kb < 4; kb++) {
            floatx4 s0 = (floatx4){0.f,0.f,0.f,0.f};
            floatx4 s1 = (floatx4){0.f,0.f,0.f,0.f};
            #pragma unroll
            for (int ks = 0; ks < 2; ks++) {
                const short8 kf = *(const short8*)
                    &Ks[(kb * 16 + li) * 64 + ((ks * 4 + quad) ^ swz) * 8];
                __builtin_amdgcn_s_setprio(1);
                s0 = __builtin_amdgcn_mfma_f32_16x16x32_bf16(kf, qf[0][ks], s0, 0, 0, 0);
                s1 = __builtin_amdgcn_mfma_f32_16x16x32_bf16(kf, qf[1][ks], s1, 0, 0, 0);
                __builtin_amdgcn_s_setprio(0);
            }
            const float4 m4 = *(const float4*)&mc[kb * 16 + quad * 4];
            {
                const float p0 = __builtin_amdgcn_exp2f(fmaf(s0[0], CSCALE, m4.x));
                const float p1 = __builtin_amdgcn_exp2f(fmaf(s0[1], CSCALE, m4.y));
                const float p2 = __builtin_amdgcn_exp2f(fmaf(s0[2], CSCALE, m4.z));
                const float p3 = __builtin_amdgcn_exp2f(fmaf(s0[3], CSCALE, m4.w));
                rs[0] += (p0 + p1) + (p2 + p3);
                ushort4v pk;
                pk[0] = f2bf(p0); pk[1] = f2bf(p1);
                pk[2] = f2bf(p2); pk[3] = f2bf(p3);
                *(ushort4v*)&Ps[w][li][kb * 16 + quad * 4] = pk;
            }
            {
                const float p0 = __builtin_amdgcn_exp2f(fmaf(s1[0], CSCALE, m4.x));
                const float p1 = __builtin_amdgcn_exp2f(fmaf(s1[1], CSCALE, m4.y));
                const float p2 = __builtin_amdgcn_exp2f(fmaf(s1[2], CSCALE, m4.z));
                const float p3 = __builtin_amdgcn_exp2f(fmaf(s1[3], CSCALE, m4.w));
                rs[1] += (p0 + p1) + (p2 + p3);
                ushort4v pk;
                pk[0] = f2bf(p0); pk[1] = f2bf(p1);
                pk[2] = f2bf(p2); pk[3] = f2bf(p3);
                *(ushort4v*)&Ps[w][16 + li][kb * 16 + quad * 4] = pk;
            }
        }

        __syncthreads();   // β2: V(t) drained; all waves done with Ks(t)/mc(t)

        if (kt + 64 < SEQ) {
            // stage K(t+1) + mc(t+1): drains at β1(t+1), overlapping PV
            #pragma unroll
            for (int j = 0; j < 2; j++) {
                const int rb = w * 16 + j * 8;
                async_copy16(Kbh + (size_t)(kt + 64 + rb + lrow8) * HD + gch * 8,
                             &Ks[rb * 64]);
            }
            if (t < 64) mc[t] = (mg[kt + 64 + t] != 0) ? -16.0f : -1.0e9f;
        }

        // ---- O^T += V^T P^T ---------------------------------------------
        #pragma unroll
        for (int ks = 0; ks < 2; ks++) {
            short8 pf[2];
            #pragma unroll
            for (int qb = 0; qb < 2; qb++)
                pf[qb] = *(const short8*)&Ps[w][qb * 16 + li][ks * 32 + quad * 8];
            __builtin_amdgcn_s_setprio(1);
            #pragma unroll
            for (int hm = 0; hm < 4; hm++) {
                const short8 vf = *(const short8*)&Vs[(hm * 16 + li) * 64 + ((ks * 4 + quad) ^ swz) * 8];
                #pragma unroll
                for (int qb = 0; qb < 2; qb++)
                    oacc[hm][qb] = __builtin_amdgcn_mfma_f32_16x16x32_bf16(
                        vf, pf[qb], oacc[hm][qb], 0, 0, 0);
            }
            __builtin_amdgcn_s_setprio(0);
        }
    }

    float linv[2];
    #pragma unroll
    for (int qb = 0; qb < 2; qb++) {
        float v = rs[qb];
        v += __shfl_xor(v, 16, 64);
        v += __shfl_xor(v, 32, 64);
        linv[qb] = 1.0f / v;
    }
    #pragma unroll
    for (int qb = 0; qb < 2; qb++) {
        const size_t row = (size_t)b * SEQ + q0 + w * 32 + qb * 16 + li;
        #pragma unroll
        for (int hm = 0; hm < 4; hm++) {
            ushort4v o;
            #pragma unroll
            for (int reg = 0; reg < 4; reg++)
                o[reg] = f2bf(oacc[hm][qb][reg] * linv[qb]);
            *(ushort4v*)&H[row * D_MODEL + h * 64 + hm * 16 + quad * 4] = o;
        }
    }
}

// ---------------------------------------------------------------------------
extern "C" void kernel_launch(void* const* d_in, const int* in_sizes, int n_in,
                              void* d_out, int out_size, void* d_ws, size_t ws_size,
                              hipStream_t stream)
{
    const float* query = (const float*)d_in[0];
    const float* key_  = (const float*)d_in[1];
    const float* value = (const float*)d_in[2];
    const int*   mask  = (const int*)  d_in[3];
    const float* Wq = (const float*)d_in[4];
    const float* bq = (const float*)d_in[5];
    const float* Wk = (const float*)d_in[6];
    const float* bk = (const float*)d_in[7];
    const float* Wv = (const float*)d_in[8];
    const float* bv = (const float*)d_in[9];
    const float* Wo = (const float*)d_in[10];
    const float* bo = (const float*)d_in[11];
    float* out = (float*)d_out;

    const size_t per = (size_t)BATCH * NHEAD * SEQ * HD;   // 8,388,608 elems
    const size_t wsz = (size_t)D_MODEL * D_MODEL;          // 1,048,576 elems
    u16* Qb  = (u16*)d_ws;          // projected Q [B,H,S,Hd]        16 MB
    u16* Kb  = Qb  + per;           // projected K [B,H,S,Hd]        16 MB
    u16* Vtb = Kb  + per;           // projected V^T [B,H,Hd,S]      16 MB
    u16* Wqb = Vtb + per;           // bf16 weights                   2 MB x4
    u16* Wkb = Wqb + wsz;
    u16* Wvb = Wkb + wsz;
    u16* Wob = Wvb + wsz;
    u16* Hb  = Wob + wsz;           // attention out [B,S,D]         16 MB
                                    // total ~72 MB

    // weights-only fp32->bf16 (activations converted inside gemm_qkv)
    cvt4<<<dim3(wsz / 2048, 4), 256, 0, stream>>>(Wq, Wk, Wv, Wo,
                                                  Wqb, Wkb, Wvb, Wob);

    gemm_qkv<<<dim3(MROWS / 128, D_MODEL / 128, 3), 256, 0, stream>>>(
        query, key_, value, Wqb, Wkb, Wvb, bq, bk, bv, Qb, Kb, Vtb);

    attn_mfma<<<dim3(SEQ / 128, BATCH * NHEAD), 256, 0, stream>>>(
        Qb, Kb, Vtb, mask, Hb);

    gemm_out<<<dim3(MROWS / 128, D_MODEL / 128), 256, 0, stream>>>(
        Hb, Wob, bo, out);
}